// Round 11
// baseline (52.876 us; speedup 1.0000x reference)
//
#include <hip/hip_runtime.h>

// LIF scan, B=65536 x L=400. Round 11: full software pipeline, single wave.
// Evidence ledger:
//   r3/r8/r9: 41.3-42.2us clean counters; r10 +nt stores: 38.8us,
//     WRITE 104MB clean (nt benign on full-line stores; r4/r6's 251MB was the
//     store-wave structure — 3x confirmed dead end).
//   FETCH ~56MB is a harness-L3 equilibrium (inter-replay poison fills), not
//     ours to reduce. Warm HBM 160MB @ 38.8us = 4.1 TB/s vs 6.3 achievable.
//   Remaining theory: per-wave phase serialization. Scan is a latency-bound
//     dependent chain (~25% issue-slot use); expand+store runs AFTER it each
//     chunk; prefetch only 1 deep.
// This round:
//   - 2-deep prefetch: chunks 0,1 loaded in prologue; iter c loads c+2.
//   - expand+store of chunk c-1 happens INSIDE iteration c, before the scan
//     in program order -> stores drain under the scan's latency bubbles.
//     bitsb double-buffered; single wave -> in-order DS, zero barriers.
//   - nt stores kept (r10 win).
// div20 = Markstein 2-fma correctly-rounded v/20 (validated r3-r10).

#define L_LEN 400
#define TC 80
#define NC 5
#define F4C 20
#define PITCHF 96
#define BIG 0x7fffffff

typedef float f4 __attribute__((ext_vector_type(4)));

__device__ __forceinline__ float div20(float v) {
    const float c = 0.05f;
    float q = v * c;
    float r = fmaf(-20.0f, q, v);
    return fmaf(r, c, q);
}

__global__ __launch_bounds__(64, 1) void lif_kernel(const float* __restrict__ I,
                                                    float* __restrict__ spikes,
                                                    float* __restrict__ hard_lat,
                                                    float* __restrict__ soft_lat) {
    __shared__ float lds_in[64 * PITCHF];     // 24576 B
    __shared__ unsigned bitsb[2][64 * 3];     // 1536 B, double-buffered
    const int j = threadIdx.x;
    const int R0 = blockIdx.x * 64;
    const char* Ib = (const char*)I + (size_t)R0 * 1600;
    char* Sb = (char*)spikes + (size_t)R0 * 1600;

    const int r0 = j / 20;
    const int k0 = j - r0 * 20;

    f4 A[F4C], Bb[F4C];

    auto load_coal = [&](int c, f4* rg) {
        int r = r0, k = k0;
        int off = r * 1600 + k * 16 + c * 320;
#pragma unroll
        for (int i = 0; i < F4C; ++i) {
            rg[i] = *reinterpret_cast<const f4*>(Ib + off);
            int kn = k + 4; bool cr = kn >= 20;
            k = cr ? kn - 20 : kn;
            r += cr ? 4 : 3;
            off += cr ? 6144 : 4864;
        }
    };

    auto write_lds = [&](const f4* rg) {
        int r = r0, k = k0;
#pragma unroll
        for (int i = 0; i < F4C; ++i) {
            *reinterpret_cast<f4*>(&lds_in[r * PITCHF + ((k ^ (r & 7)) << 2)]) = rg[i];
            int kn = k + 4; bool cr = kn >= 20;
            k = cr ? kn - 20 : kn;
            r += cr ? 4 : 3;
        }
    };

    auto expand_store = [&](int c, const unsigned* bb) {
        int r = r0, k = k0;
        int off = r * 1600 + k * 16 + c * 320;
#pragma unroll
        for (int i = 0; i < F4C; ++i) {
            unsigned w = bb[r * 3 + (k >> 3)];
            int sh = (k & 7) * 4;
            f4 s;
            s.x = (float)((w >> (sh + 0)) & 1u);
            s.y = (float)((w >> (sh + 1)) & 1u);
            s.z = (float)((w >> (sh + 2)) & 1u);
            s.w = (float)((w >> (sh + 3)) & 1u);
            __builtin_nontemporal_store(s, reinterpret_cast<f4*>(Sb + off));
            int kn = k + 4; bool cr = kn >= 20;
            k = cr ? kn - 20 : kn;
            r += cr ? 4 : 3;
            off += cr ? 6144 : 4864;
        }
    };

    // prologue: 2-deep prefetch; chunk0 into LDS
    load_coal(0, A);
    load_coal(1, Bb);
    write_lds(A);

    float v = 0.0f;
    int num = 0, cnt = 0, first = BIG;
    float* myrow = &lds_in[j * PITCHF];
    const int jx = j & 7;

#pragma unroll 1
    for (int c = 0; c < NC; ++c) {
        // issue next-next chunk's loads first (deepest prefetch)
        if (c + 2 < NC) load_coal(c + 2, (c & 1) ? Bb : A);
        // previous chunk's expand+store: independent of this scan -> the
        // scheduler drains it into the scan chain's latency bubbles
        if (c > 0) expand_store(c - 1, bitsb[(c - 1) & 1]);

        // ---- scan chunk c from LDS (conflict-free swizzled b128 reads) ----
        unsigned b0 = 0, b1 = 0, b2 = 0;
        int numL = 0;
#pragma unroll
        for (int k = 0; k < F4C; ++k) {
            f4 x4 = *reinterpret_cast<const f4*>(&myrow[((k ^ jx) << 2)]);
#pragma unroll
            for (int m = 0; m < 4; ++m) {
                const int tl = k * 4 + m;
                float x = x4[m];
                // reference association: v = v + ((-v/20) + x)
                float d  = x - div20(v);
                float vn = v + d;
                bool fire = vn >= 1.0f;
                numL = fire ? numL + tl : numL;
                if (tl < 32)      b0 |= fire ? (1u << tl) : 0u;
                else if (tl < 64) b1 |= fire ? (1u << (tl - 32)) : 0u;
                else              b2 |= fire ? (1u << (tl - 64)) : 0u;
                v = fire ? 0.0f : vn;
            }
        }
        int cntC = __builtin_popcount(b0) + __builtin_popcount(b1) +
                   __builtin_popcount(b2);
        int fl = b0 ? __builtin_ctz(b0)
               : (b1 ? 32 + __builtin_ctz(b1)
               : (b2 ? 64 + __builtin_ctz(b2) : -1));
        int cbase = c * TC;
        num += numL + cbase * cntC;
        cnt += cntC;
        first = min(first, fl >= 0 ? cbase + fl : BIG);

        bitsb[c & 1][j * 3 + 0] = b0;
        bitsb[c & 1][j * 3 + 1] = b1;
        bitsb[c & 1][j * 3 + 2] = b2;

        // stage chunk c+1 into LDS (in-order DS: after this scan's reads)
        if (c + 1 < NC) write_lds((c & 1) ? A : Bb);
    }
    // epilogue: last chunk's stores
    expand_store(NC - 1, bitsb[(NC - 1) & 1]);

    const int row = R0 + j;
    hard_lat[row] = (float)(first == BIG ? 0 : first);
    soft_lat[row] = (float)num / ((float)cnt + 1e-6f);
}

extern "C" void kernel_launch(void* const* d_in, const int* in_sizes, int n_in,
                              void* d_out, int out_size, void* d_ws, size_t ws_size,
                              hipStream_t stream) {
    const float* I = (const float*)d_in[0];
    int B = in_sizes[0] / L_LEN;  // 65536

    float* spk = (float*)d_out;
    float* hard = spk + (size_t)B * L_LEN;
    float* soft = hard + B;

    dim3 block(64);
    dim3 grid(B / 64);
    hipLaunchKernelGGL(lif_kernel, grid, block, 0, stream, I, spk, hard, soft);
}

// Round 12
// 40.740 us; speedup vs baseline: 1.2979x; 1.2979x over previous
//
#include <hip/hip_runtime.h>

// LIF scan, B=65536 x L=400. Round 12: r11's pipeline schedule, STATIC buffers.
// Evidence ledger:
//   r10 (base): 38.8us, FETCH 56MB, WRITE 104MB clean, nt full-line stores.
//   r11: same memory counters but 52.9us, VGPR 224 — rolled loop + runtime
//     buffer select ((c&1)?Bb:A) = rule-#20 register-array shuffle storm.
//     The overlap schedule itself was never fairly tested.
// This round: hand-unrolled NC=5, every buffer reference static (A/B named at
// each call site; 2 buffers suffice: write_lds frees one per iteration).
// Per-chunk order: load(c+2) -> expand_store(c-1) (independent; drains into
// scan's latency bubbles) -> scan(c) -> bits->LDS -> write_lds(c+1).
// nt stores kept (r10). div20 = Markstein 2-fma correctly-rounded v/20.

#define L_LEN 400
#define TC 80
#define NC 5
#define F4C 20
#define PITCHF 96
#define BIG 0x7fffffff

typedef float f4 __attribute__((ext_vector_type(4)));

__device__ __forceinline__ float div20(float v) {
    const float c = 0.05f;
    float q = v * c;
    float r = fmaf(-20.0f, q, v);
    return fmaf(r, c, q);
}

__global__ __launch_bounds__(64, 1) void lif_kernel(const float* __restrict__ I,
                                                    float* __restrict__ spikes,
                                                    float* __restrict__ hard_lat,
                                                    float* __restrict__ soft_lat) {
    __shared__ float lds_in[64 * PITCHF];     // 24576 B
    __shared__ unsigned bitsb[2][64 * 3];     // 1536 B double-buffered
    const int j = threadIdx.x;
    const int R0 = blockIdx.x * 64;
    const char* Ib = (const char*)I + (size_t)R0 * 1600;
    char* Sb = (char*)spikes + (size_t)R0 * 1600;

    const int r0 = j / 20;
    const int k0 = j - r0 * 20;
    const int jx = j & 7;
    float* myrow = &lds_in[j * PITCHF];

    float v = 0.0f;
    int num = 0, cnt = 0, first = BIG;

    f4 A[F4C], B[F4C];

    auto load_coal = [&](int c, f4* rg) {   // c constant at every call site
        int r = r0, k = k0;
        int off = r * 1600 + k * 16 + c * 320;
#pragma unroll
        for (int i = 0; i < F4C; ++i) {
            rg[i] = *reinterpret_cast<const f4*>(Ib + off);
            int kn = k + 4; bool cr = kn >= 20;
            k = cr ? kn - 20 : kn;
            r += cr ? 4 : 3;
            off += cr ? 6144 : 4864;
        }
    };

    auto write_lds = [&](const f4* rg) {
        int r = r0, k = k0;
#pragma unroll
        for (int i = 0; i < F4C; ++i) {
            *reinterpret_cast<f4*>(&lds_in[r * PITCHF + ((k ^ (r & 7)) << 2)]) = rg[i];
            int kn = k + 4; bool cr = kn >= 20;
            k = cr ? kn - 20 : kn;
            r += cr ? 4 : 3;
        }
    };

    auto expand_store = [&](int c, const unsigned* bb) {
        int r = r0, k = k0;
        int off = r * 1600 + k * 16 + c * 320;
#pragma unroll
        for (int i = 0; i < F4C; ++i) {
            unsigned w = bb[r * 3 + (k >> 3)];
            int sh = (k & 7) * 4;
            f4 s;
            s.x = (float)((w >> (sh + 0)) & 1u);
            s.y = (float)((w >> (sh + 1)) & 1u);
            s.z = (float)((w >> (sh + 2)) & 1u);
            s.w = (float)((w >> (sh + 3)) & 1u);
            __builtin_nontemporal_store(s, reinterpret_cast<f4*>(Sb + off));
            int kn = k + 4; bool cr = kn >= 20;
            k = cr ? kn - 20 : kn;
            r += cr ? 4 : 3;
            off += cr ? 6144 : 4864;
        }
    };

    auto scan = [&](int c, unsigned* dst) {  // c constant at every call site
        unsigned b0 = 0, b1 = 0, b2 = 0;
        int numL = 0;
#pragma unroll
        for (int k = 0; k < F4C; ++k) {
            f4 x4 = *reinterpret_cast<const f4*>(&myrow[((k ^ jx) << 2)]);
#pragma unroll
            for (int m = 0; m < 4; ++m) {
                const int tl = k * 4 + m;
                float x = x4[m];
                // reference association: v = v + ((-v/20) + x)
                float d  = x - div20(v);
                float vn = v + d;
                bool fire = vn >= 1.0f;
                numL = fire ? numL + tl : numL;
                if (tl < 32)      b0 |= fire ? (1u << tl) : 0u;
                else if (tl < 64) b1 |= fire ? (1u << (tl - 32)) : 0u;
                else              b2 |= fire ? (1u << (tl - 64)) : 0u;
                v = fire ? 0.0f : vn;
            }
        }
        int cntC = __builtin_popcount(b0) + __builtin_popcount(b1) +
                   __builtin_popcount(b2);
        int fl = b0 ? __builtin_ctz(b0)
               : (b1 ? 32 + __builtin_ctz(b1)
               : (b2 ? 64 + __builtin_ctz(b2) : -1));
        int cbase = c * TC;
        num += numL + cbase * cntC;
        cnt += cntC;
        first = min(first, fl >= 0 ? cbase + fl : BIG);
        dst[j * 3 + 0] = b0;
        dst[j * 3 + 1] = b1;
        dst[j * 3 + 2] = b2;
    };

    // ---- fully static pipeline ----
    load_coal(0, A);
    load_coal(1, B);
    write_lds(A);                       // chunk0 -> LDS; A free

    // c=0
    load_coal(2, A);
    scan(0, bitsb[0]);
    write_lds(B);                       // chunk1 -> LDS; B free
    // c=1
    load_coal(3, B);
    expand_store(0, bitsb[0]);
    scan(1, bitsb[1]);
    write_lds(A);                       // chunk2 -> LDS; A free
    // c=2
    load_coal(4, A);
    expand_store(1, bitsb[1]);
    scan(2, bitsb[0]);
    write_lds(B);                       // chunk3 -> LDS
    // c=3
    expand_store(2, bitsb[0]);
    scan(3, bitsb[1]);
    write_lds(A);                       // chunk4 -> LDS
    // c=4
    expand_store(3, bitsb[1]);
    scan(4, bitsb[0]);
    expand_store(4, bitsb[0]);

    const int row = R0 + j;
    hard_lat[row] = (float)(first == BIG ? 0 : first);
    soft_lat[row] = (float)num / ((float)cnt + 1e-6f);
}

extern "C" void kernel_launch(void* const* d_in, const int* in_sizes, int n_in,
                              void* d_out, int out_size, void* d_ws, size_t ws_size,
                              hipStream_t stream) {
    const float* I = (const float*)d_in[0];
    int B = in_sizes[0] / L_LEN;  // 65536

    float* spk = (float*)d_out;
    float* hard = spk + (size_t)B * L_LEN;
    float* soft = hard + B;

    dim3 block(64);
    dim3 grid(B / 64);
    hipLaunchKernelGGL(lif_kernel, grid, block, 0, stream, I, spk, hard, soft);
}